// Round 13
// baseline (355.347 us; speedup 1.0000x reference)
//
#include <hip/hip_runtime.h>
#include <stdint.h>

typedef __attribute__((ext_vector_type(8))) short bf16x8;
typedef __attribute__((ext_vector_type(4))) float f32x4;

#define TN 2.45f          // normalized filter threshold (units of s_p)
#define PMARG 0.13f       // exact-rescore pool margin below bf16 rank-32
#define CAP 224
#define SORT2 128

__device__ inline float bf2f(unsigned short u) { return __uint_as_float(((unsigned int)u) << 16); }
__device__ inline unsigned short f2bf(float f) {
    unsigned int x = __float_as_uint(f);
    return (unsigned short)((x + 0x7FFFu + ((x >> 16) & 1u)) >> 16);  // RNE
}

template <typename T>
__device__ inline void gload16(const T* g, T* l) {
    __builtin_amdgcn_global_load_lds((const __attribute__((address_space(1))) void*)g,
                                     (__attribute__((address_space(3))) void*)l, 16, 0, 0);
}

// ---- T1: x [16][512][256] -> xT [4096][512] (f32+bf16) + ||x_p||^2 + per-channel S/Q ----
__global__ __launch_bounds__(256) void t1_x(const float* __restrict__ x, float* __restrict__ xTf,
                                            unsigned short* __restrict__ xTb, float* __restrict__ thrS,
                                            double* __restrict__ S, double* __restrict__ Q) {
    __shared__ float tile[64][65];
    int b = blockIdx.z, c0 = blockIdx.x * 64, hw0 = blockIdx.y * 64;
    int tid = threadIdx.x, g = tid >> 6, ln = tid & 63;
    for (int i = 0; i < 16; i++) {
        int cl = g * 16 + i;
        tile[cl][ln] = x[(size_t)(b * 512 + c0 + cl) * 256 + hw0 + ln];
    }
    __syncthreads();
    float s1 = 0.0f, s2 = 0.0f;  // channel c0+ln over this wave's 16 hw positions
    for (int i = 0; i < 16; i++) {
        int hl = g * 16 + i;
        float v = tile[ln][hl];
        size_t o = (size_t)(b * 256 + hw0 + hl) * 512 + c0 + ln;
        xTf[o] = v;
        xTb[o] = f2bf(v);
        s1 += v;
        s2 += v * v;
        float s = v * v;  // per-pixel ||x||^2 partial (lanes = channels)
        for (int off = 32; off; off >>= 1) s += __shfl_down(s, off, 64);
        if (ln == 0) atomicAdd(&thrS[b * 256 + hw0 + hl], s);
    }
    atomicAdd(&S[c0 + ln], (double)s1);
    atomicAdd(&Q[c0 + ln], (double)s2);
}

// ---------------- T2: enc_w f32 -> bf16 ----------------
__global__ __launch_bounds__(256) void t2_encw(const float* __restrict__ w, unsigned short* __restrict__ wb) {
    size_t i = ((size_t)blockIdx.x * 256 + threadIdx.x) * 8;
    const float4* s = (const float4*)(w + i);
    float4 a = s[0], b = s[1];
    unsigned int p0 = (unsigned)f2bf(a.x) | ((unsigned)f2bf(a.y) << 16);
    unsigned int p1 = (unsigned)f2bf(a.z) | ((unsigned)f2bf(a.w) << 16);
    unsigned int p2 = (unsigned)f2bf(b.x) | ((unsigned)f2bf(b.y) << 16);
    unsigned int p3 = (unsigned)f2bf(b.z) | ((unsigned)f2bf(b.w) << 16);
    *(uint4*)(wb + i) = make_uint4(p0, p1, p2, p3);
}

// ---------------- T3: dec_w [512][16384] -> dec_wT [16384][512] bf16 ----------------
__global__ __launch_bounds__(256) void t3_decw(const float* __restrict__ w, unsigned short* __restrict__ wT) {
    __shared__ float tile[64][65];
    int l0 = blockIdx.x * 64, d0 = blockIdx.y * 64;
    int tid = threadIdx.x, g = tid >> 6, ln = tid & 63;
    for (int i = 0; i < 16; i++) {
        int dl = g * 16 + i;
        tile[dl][ln] = w[(size_t)(d0 + dl) * 16384 + l0 + ln];
    }
    __syncthreads();
    for (int i = 0; i < 16; i++) {
        int ll = g * 16 + i;
        wT[(size_t)(l0 + ll) * 512 + d0 + ln] = f2bf(tile[ln][ll]);
    }
}

// ---- GEMM: 128x128 tile, 256 thr, 2-buf (2 blocks/CU), wait-before-stage, 2 sub-phases
//      with setprio (T5) + T2 swizzle + XCD swizzle ----
#define SBAR                                   \
    __builtin_amdgcn_sched_barrier(0);         \
    __builtin_amdgcn_s_barrier();              \
    __builtin_amdgcn_sched_barrier(0);
#define VMW0 { asm volatile("s_waitcnt vmcnt(0)" ::: "memory"); __builtin_amdgcn_sched_barrier(0); }
#define LGKM0 { asm volatile("s_waitcnt lgkmcnt(0)" ::: "memory"); __builtin_amdgcn_sched_barrier(0); }

__global__ __launch_bounds__(256) void k_gemm(const unsigned short* __restrict__ xbf,
                                              const unsigned short* __restrict__ wbf,
                                              const float* __restrict__ thrS,
                                              int* __restrict__ cnt, unsigned int* __restrict__ cand) {
    __shared__ __align__(16) unsigned short As[2][128 * 64];  // 2 x 16KB
    __shared__ __align__(16) unsigned short Bs[2][128 * 64];  // 2 x 16KB (tot 64KB -> 2 blocks/CU)
    int tid = threadIdx.x, wid = tid >> 6, lane = tid & 63;

    // XCD swizzle (bijective, 4096 blocks): each XCD owns 512 consecutive lin -> 16 n-blocks
    // (2048 latents -> 2MB B slice, L2-resident) x all 32 m-blocks.
    int lin = blockIdx.x + blockIdx.y * gridDim.x;   // grid (128 n, 32 m)
    int swz = (lin & 7) * 512 + (lin >> 3);
    int bx = swz >> 5;          // n-block 0..127
    int by = swz & 31;          // m-block 0..31
    int m0 = by * 128, n0 = bx * 128;
    int wr = wid >> 1, wc = wid & 1;   // 2x2 waves, per-wave 64x64

    f32x4 acc[4][4];
#pragma unroll
    for (int mi = 0; mi < 4; mi++)
#pragma unroll
        for (int ni = 0; ni < 4; ni++)
#pragma unroll
            for (int j = 0; j < 4; j++) acc[mi][ni][j] = 0.0f;

    int srow = lane >> 3;
    int scol = (((lane & 7) ^ (lane >> 3)) << 3);  // involution; read side XORs (row&7)<<3

#define STAGE(bufi, kt)                                                                           \
    {                                                                                             \
        unsigned short* Ad = &As[bufi][0];                                                        \
        unsigned short* Bd = &Bs[bufi][0];                                                        \
        _Pragma("unroll")                                                                         \
        for (int i_ = 0; i_ < 4; i_++) {                                                          \
            int ch_ = wid * 4 + i_;                                                               \
            gload16(xbf + (size_t)(m0 + ch_ * 8 + srow) * 512 + (kt) + scol, Ad + ch_ * 512);     \
            gload16(wbf + (size_t)(n0 + ch_ * 8 + srow) * 512 + (kt) + scol, Bd + ch_ * 512);     \
        }                                                                                         \
    }

    STAGE(0, 0)
#pragma unroll
    for (int t = 0; t < 8; t++) {
        int cur = t & 1;
        VMW0                        // waits ONLY tile t's 8 loads (issued one full iter earlier)
        SBAR                        // tile t visible to all; prev readers of buf cur^1 retired
        if (t < 7) STAGE(cur ^ 1, (t + 1) * 64)   // prefetch lands during this iter + next wait
        const unsigned short* Ac = &As[cur][0];
        const unsigned short* Bc = &Bs[cur][0];
#pragma unroll
        for (int kk = 0; kk < 2; kk++) {          // 2 sub-phases: role-split for setprio
            int kc = kk * 32 + (lane >> 4) * 8;
            bf16x8 a[4], b[4];
#pragma unroll
            for (int mi = 0; mi < 4; mi++) {
                int row = wr * 64 + mi * 16 + (lane & 15);
                a[mi] = *(const bf16x8*)&Ac[row * 64 + (kc ^ ((row & 7) << 3))];
            }
#pragma unroll
            for (int ni = 0; ni < 4; ni++) {
                int row = wc * 64 + ni * 16 + (lane & 15);
                b[ni] = *(const bf16x8*)&Bc[row * 64 + (kc ^ ((row & 7) << 3))];
            }
            LGKM0                   // rule #18: fence ds_reads before reg-only MFMA
            __builtin_amdgcn_s_setprio(1);
#pragma unroll
            for (int mi = 0; mi < 4; mi++)
#pragma unroll
                for (int ni = 0; ni < 4; ni++)
                    acc[mi][ni] = __builtin_amdgcn_mfma_f32_16x16x32_bf16(a[mi], b[ni], acc[mi][ni], 0, 0, 0);
            __builtin_amdgcn_s_setprio(0);
            if (kk == 0) SBAR       // mid-iteration phase boundary
        }
    }
#undef STAGE

    // filter epilogue (outside the pipeline)
#pragma unroll
    for (int mi = 0; mi < 4; mi++)
#pragma unroll
        for (int j = 0; j < 4; j++) {
            int pixel = m0 + wr * 64 + mi * 16 + (lane >> 4) * 4 + j;
            float tv = TN * sqrtf(thrS[pixel] * (1.0f / 512.0f));
#pragma unroll
            for (int ni = 0; ni < 4; ni++) {
                float v = acc[mi][ni][j];
                if (v >= tv) {
                    int lat = n0 + wc * 64 + ni * 16 + (lane & 15);
                    int slot = atomicAdd(&cnt[pixel], 1);
                    if (slot < CAP) cand[pixel * CAP + slot] = ((unsigned)f2bf(v) << 16) | (unsigned)lat;
                }
            }
        }
}

// ---- top-32 + decode fused: binary-search bf16 rank-32, exact seqFMA rescore pool, sort,
//      then sparse decode + l2 using xrow already in LDS ----
__global__ __launch_bounds__(256) void k_topk(const float* __restrict__ xTf, const float* __restrict__ enc_w,
                                              const float* __restrict__ enc_b, const int* __restrict__ cnt,
                                              const unsigned int* __restrict__ cand,
                                              const unsigned short* __restrict__ dwT,
                                              const float* __restrict__ dec_b,
                                              float* __restrict__ out_acts, float* __restrict__ out_idx,
                                              float* __restrict__ out_sae, double* __restrict__ l2acc) {
    __shared__ __align__(16) float xrow[512];
    __shared__ unsigned long long skey2[SORT2]; // (0xFFFFFFFF-f32bits)<<32 | lat : asc => desc value
    __shared__ int npool;
    __shared__ float sa[32];
    __shared__ int si[32];
    __shared__ double red[256];
    int p = blockIdx.x, tid = threadIdx.x;
    for (int i = tid; i < 512; i += 256) xrow[i] = xTf[(size_t)p * 512 + i];
    if (tid < SORT2) skey2[tid] = ~0ull;
    if (tid == 0) npool = 0;
    int c = cnt[p];
    if (c > CAP) c = CAP;
    unsigned int pk = (tid < c) ? cand[p * CAP + tid] : 0u;
    unsigned int bfb = pk >> 16;  // bf16 bits of score (0 if no candidate)
    // binary search: largest T with count(bfb >= T) >= 32
    int lo = 0, hi = 65535;
    for (int it = 0; it < 16; it++) {
        int mid = (lo + hi + 1) >> 1;
        int n = __syncthreads_count(tid < c && bfb >= (unsigned)mid);
        if (n >= 32) lo = mid; else hi = mid - 1;
    }
    float pthr = bf2f((unsigned short)lo) - PMARG;
    __syncthreads();
    // exact rescore (XLA:CPU-matching f32 sequential FMA, c ascending) of near-top pool
    if (tid < c && bf2f((unsigned short)bfb) >= pthr) {
        int slot = atomicAdd(&npool, 1);
        if (slot < SORT2) {
            int lat = (int)(pk & 16383u);
            const float4* w4 = (const float4*)(enc_w + (size_t)lat * 512);
            const float4* x4 = (const float4*)xrow;
            float acc = 0.0f;
            for (int q = 0; q < 128; q++) {
                float4 w = w4[q];
                float4 xv = x4[q];
                acc = __fmaf_rn(xv.x, w.x, acc);
                acc = __fmaf_rn(xv.y, w.y, acc);
                acc = __fmaf_rn(xv.z, w.z, acc);
                acc = __fmaf_rn(xv.w, w.w, acc);
            }
            float pre = __fadd_rn(acc, enc_b[lat]);
            unsigned long long key;
            if (pre > 0.0f) {
                key = ((unsigned long long)(0xFFFFFFFFu - __float_as_uint(pre)) << 32) | (unsigned)lat;
            } else {
                key = 0xFFFFFFFF00000000ull | (unsigned)lat;
            }
            skey2[slot] = key;
        }
    }
    __syncthreads();
    // bitonic ascending sort of skey2[0..128)
    for (int ks = 2; ks <= SORT2; ks <<= 1) {
        for (int jj = ks >> 1; jj > 0; jj >>= 1) {
            int i = tid;
            if (i < SORT2) {
                int ixj = i ^ jj;
                if (ixj > i) {
                    bool up = ((i & ks) == 0);
                    unsigned long long a = skey2[i], b2 = skey2[ixj];
                    if (up ? (a > b2) : (a < b2)) { skey2[i] = b2; skey2[ixj] = a; }
                }
            }
            __syncthreads();
        }
    }
    int b = p >> 8, hw = p & 255;
    if (tid < 32) {
        unsigned long long key = skey2[tid];
        unsigned int fb = 0xFFFFFFFFu - (unsigned int)(key >> 32);
        float act = fmaxf(__uint_as_float(fb), 0.0f);
        int lat = (int)(key & 16383u);
        sa[tid] = act;
        si[tid] = lat;
        out_acts[(size_t)b * 8192 + tid * 256 + hw] = act;
        out_idx[(size_t)b * 8192 + tid * 256 + hw] = (float)lat;
    }
    __syncthreads();
    // ---- fused decode + l2 (xrow holds x[b,:,hw] exactly) ----
    float a0 = dec_b[tid], a1 = dec_b[tid + 256];
    for (int j = 0; j < 32; j++) {
        float a = sa[j];
        const unsigned short* r = dwT + (size_t)si[j] * 512;
        a0 += a * bf2f(r[tid]);
        a1 += a * bf2f(r[tid + 256]);
    }
    size_t o0 = (size_t)b * 131072 + (size_t)tid * 256 + hw;
    size_t o1 = o0 + 65536;
    out_sae[o0] = a0;
    out_sae[o1] = a1;
    float e0 = a0 - xrow[tid], e1 = a1 - xrow[tid + 256];
    red[tid] = (double)e0 * e0 + (double)e1 * e1;
    __syncthreads();
    for (int s = 128; s; s >>= 1) {
        if (tid < s) red[tid] += red[tid + s];
        __syncthreads();
    }
    if (tid == 0) atomicAdd(l2acc, red[0]);
}

// ---------------- finalize fvu ----------------
__global__ __launch_bounds__(256) void k_fin(const double* __restrict__ l2, const double* __restrict__ S,
                                             const double* __restrict__ Q, float* __restrict__ out_sc) {
    __shared__ double red[256];
    int tid = threadIdx.x;
    double tv = 0;
    for (int c = tid; c < 512; c += 256) tv += Q[c] - S[c] * S[c] * (1.0 / 4096.0);
    red[tid] = tv;
    __syncthreads();
    for (int s = 128; s; s >>= 1) {
        if (tid < s) red[tid] += red[tid + s];
        __syncthreads();
    }
    if (tid == 0) {
        double fvu = l2[0] / red[0];
        out_sc[0] = (float)fvu;
        out_sc[1] = 0.0f;
        out_sc[2] = 0.0f;
    }
}

extern "C" void kernel_launch(void* const* d_in, const int* in_sizes, int n_in,
                              void* d_out, int out_size, void* d_ws, size_t ws_size,
                              hipStream_t stream) {
    const float* x = (const float*)d_in[0];
    const float* enc_w = (const float*)d_in[1];
    const float* enc_b = (const float*)d_in[2];
    const float* dec_w = (const float*)d_in[3];
    const float* dec_b = (const float*)d_in[4];
    (void)in_sizes; (void)n_in; (void)out_size; (void)ws_size;

    char* ws = (char*)d_ws;
    float* xTf = (float*)ws;                                  //  8 MB
    unsigned short* xTb = (unsigned short*)(ws + 8388608);    //  4 MB
    unsigned short* ewb = (unsigned short*)(ws + 12582912);   // 16 MB
    unsigned short* dwT = (unsigned short*)(ws + 29360128);   // 16 MB
    unsigned int* cand = (unsigned int*)(ws + 46137344);      //  3.67 MB (4096*224*4)
    // contiguous zero-init region: cnt | thrS | S | Q | l2
    int* cnt = (int*)(ws + 49807360);                         // 16 KB
    float* thrS = (float*)(ws + 49823744);                    // 16 KB
    double* S = (double*)(ws + 49840128);                     //  4 KB
    double* Q = (double*)(ws + 49844224);                     //  4 KB
    double* l2 = (double*)(ws + 49848320);                    //  8 B

    float* out = (float*)d_out;   // reference outputs are float32
    float* out_sae = out;
    float* out_acts = out + 2097152;
    float* out_idx = out + 2228224;
    float* out_sc = out + 2359296;

    hipMemsetAsync(cnt, 0, 16384 + 16384 + 4096 + 4096 + 8, stream);

    t1_x<<<dim3(8, 4, 16), 256, 0, stream>>>(x, xTf, xTb, thrS, S, Q);
    t2_encw<<<4096, 256, 0, stream>>>(enc_w, ewb);
    t3_decw<<<dim3(256, 8), 256, 0, stream>>>(dec_w, dwT);
    k_gemm<<<dim3(128, 32), 256, 0, stream>>>(xTb, ewb, thrS, cnt, cand);
    k_topk<<<4096, 256, 0, stream>>>(xTf, enc_w, enc_b, cnt, cand, dwT, dec_b,
                                     out_acts, out_idx, out_sae, l2);
    k_fin<<<1, 256, 0, stream>>>(l2, S, Q, out_sc);
}

// Round 14
// 350.690 us; speedup vs baseline: 1.0133x; 1.0133x over previous
//
#include <hip/hip_runtime.h>
#include <stdint.h>

typedef __attribute__((ext_vector_type(8))) short bf16x8;
typedef __attribute__((ext_vector_type(4))) float f32x4;

#define TN 2.45f          // normalized filter threshold (units of s_p)
#define PMARG 0.13f       // exact-rescore pool margin below bf16 rank-32
#define CAP 224
#define SORT2 128

__device__ inline float bf2f(unsigned short u) { return __uint_as_float(((unsigned int)u) << 16); }
__device__ inline unsigned short f2bf(float f) {
    unsigned int x = __float_as_uint(f);
    return (unsigned short)((x + 0x7FFFu + ((x >> 16) & 1u)) >> 16);  // RNE
}

template <typename T>
__device__ inline void gload16(const T* g, T* l) {
    __builtin_amdgcn_global_load_lds((const __attribute__((address_space(1))) void*)g,
                                     (__attribute__((address_space(3))) void*)l, 16, 0, 0);
}

// ---- T1: x [16][512][256] -> xT [4096][512] (f32+bf16) + ||x_p||^2 + per-channel S/Q ----
__global__ __launch_bounds__(256) void t1_x(const float* __restrict__ x, float* __restrict__ xTf,
                                            unsigned short* __restrict__ xTb, float* __restrict__ thrS,
                                            double* __restrict__ S, double* __restrict__ Q) {
    __shared__ float tile[64][65];
    int b = blockIdx.z, c0 = blockIdx.x * 64, hw0 = blockIdx.y * 64;
    int tid = threadIdx.x, g = tid >> 6, ln = tid & 63;
    for (int i = 0; i < 16; i++) {
        int cl = g * 16 + i;
        tile[cl][ln] = x[(size_t)(b * 512 + c0 + cl) * 256 + hw0 + ln];
    }
    __syncthreads();
    float s1 = 0.0f, s2 = 0.0f;
    for (int i = 0; i < 16; i++) {
        int hl = g * 16 + i;
        float v = tile[ln][hl];
        size_t o = (size_t)(b * 256 + hw0 + hl) * 512 + c0 + ln;
        xTf[o] = v;
        xTb[o] = f2bf(v);
        s1 += v;
        s2 += v * v;
        float s = v * v;
        for (int off = 32; off; off >>= 1) s += __shfl_down(s, off, 64);
        if (ln == 0) atomicAdd(&thrS[b * 256 + hw0 + hl], s);
    }
    atomicAdd(&S[c0 + ln], (double)s1);
    atomicAdd(&Q[c0 + ln], (double)s2);
}

// ---------------- T2: enc_w f32 -> bf16 ----------------
__global__ __launch_bounds__(256) void t2_encw(const float* __restrict__ w, unsigned short* __restrict__ wb) {
    size_t i = ((size_t)blockIdx.x * 256 + threadIdx.x) * 8;
    const float4* s = (const float4*)(w + i);
    float4 a = s[0], b = s[1];
    unsigned int p0 = (unsigned)f2bf(a.x) | ((unsigned)f2bf(a.y) << 16);
    unsigned int p1 = (unsigned)f2bf(a.z) | ((unsigned)f2bf(a.w) << 16);
    unsigned int p2 = (unsigned)f2bf(b.x) | ((unsigned)f2bf(b.y) << 16);
    unsigned int p3 = (unsigned)f2bf(b.z) | ((unsigned)f2bf(b.w) << 16);
    *(uint4*)(wb + i) = make_uint4(p0, p1, p2, p3);
}

// ---------------- T3: dec_w [512][16384] -> dec_wT [16384][512] bf16 ----------------
__global__ __launch_bounds__(256) void t3_decw(const float* __restrict__ w, unsigned short* __restrict__ wT) {
    __shared__ float tile[64][65];
    int l0 = blockIdx.x * 64, d0 = blockIdx.y * 64;
    int tid = threadIdx.x, g = tid >> 6, ln = tid & 63;
    for (int i = 0; i < 16; i++) {
        int dl = g * 16 + i;
        tile[dl][ln] = w[(size_t)(d0 + dl) * 16384 + l0 + ln];
    }
    __syncthreads();
    for (int i = 0; i < 16; i++) {
        int ll = g * 16 + i;
        wT[(size_t)(l0 + ll) * 512 + d0 + ln] = f2bf(tile[ln][ll]);
    }
}

// ---- GEMM: 256x256 tile, 8 waves, 8-phase counted-vmcnt schedule (m201-style, K-split halves) ----
// LDS: A/B each [4 slots][256 rows][32 k] bf16 (4x16KB); half s=2t+kk -> slot s%4.
// Per tile t: 4 phases (kk,mihalf). Gates (per-wave vmcnt queue audit):
//   prologue issues 12 loads: A(0,0) B(0,0) A(0,1) B(0,1) A(1,0) B(1,0)  [2 loads each]
//   ph0(u): vmcnt(8) forces A(u,0),B(u,0) [queue<=12]; u=7: vmcnt(4) [queue=8]
//   ph2(u): vmcnt(8) forces A(u,1),B(u,1) [queue<=12]; u=7: vmcnt(0)
//   issues: ph0->A(u+1,1), ph1->B(u+1,1), ph2->A(u+2,0), ph3->B(u+2,0) (guarded)
//   slot safety: issue at phase p overwrites half last read at phase p-1, after p's barrier.
#define SBAR                                   \
    __builtin_amdgcn_sched_barrier(0);         \
    __builtin_amdgcn_s_barrier();              \
    __builtin_amdgcn_sched_barrier(0);
#define VMW8 { asm volatile("s_waitcnt vmcnt(8)" ::: "memory"); __builtin_amdgcn_sched_barrier(0); }
#define VMW4 { asm volatile("s_waitcnt vmcnt(4)" ::: "memory"); __builtin_amdgcn_sched_barrier(0); }
#define VMW0 { asm volatile("s_waitcnt vmcnt(0)" ::: "memory"); __builtin_amdgcn_sched_barrier(0); }
#define LGKM0 { asm volatile("s_waitcnt lgkmcnt(0)" ::: "memory"); __builtin_amdgcn_sched_barrier(0); }

__global__ __launch_bounds__(512, 2) void k_gemm(const unsigned short* __restrict__ xbf,
                                                 const unsigned short* __restrict__ wbf,
                                                 const float* __restrict__ thrS,
                                                 int* __restrict__ cnt, unsigned int* __restrict__ cand) {
    __shared__ __align__(16) unsigned short As[4][256 * 32];  // 64KB
    __shared__ __align__(16) unsigned short Bs[4][256 * 32];  // 64KB
    int tid = threadIdx.x, wid = tid >> 6, lane = tid & 63;

    // XCD swizzle (bijective, 1024 blocks = 8 x 128): XCD k owns 8 n-panels (2MB B slice)
    int lin = blockIdx.x + blockIdx.y * gridDim.x;   // grid (64 n, 16 m)
    int swz = (lin & 7) * 128 + (lin >> 3);
    int nb = swz >> 4;          // n-panel 0..63
    int mb = swz & 15;          // m-panel 0..15
    int m0 = mb * 256, n0 = nb * 256;
    int wr = wid >> 2, wc = wid & 3;   // per-wave 128(M) x 64(N)

    f32x4 acc[8][4];
#pragma unroll
    for (int mi = 0; mi < 8; mi++)
#pragma unroll
        for (int ni = 0; ni < 4; ni++)
#pragma unroll
            for (int j = 0; j < 4; j++) acc[mi][ni][j] = 0.0f;

    // staging: chunk = 16 rows x 32 k = 1KB; 16 chunks/half; wave does chunks 2*wid, 2*wid+1.
    // lane -> row = ch*16 + (lane>>2), src k pre-swizzled: ((lane&3) ^ ((row>>1)&3))*8
    // LDS dest linear: base + ch*512 + lane*8 elems == row*32 + (lane&3)*8  (verified identity)
#define STAGE_A(t_, kk_) {                                                                     \
        unsigned short* Ad = &As[(2 * (t_) + (kk_)) & 3][0];                                   \
        _Pragma("unroll")                                                                      \
        for (int i_ = 0; i_ < 2; i_++) {                                                       \
            int ch_ = wid * 2 + i_;                                                            \
            int row_ = ch_ * 16 + (lane >> 2);                                                 \
            int kc_ = (((lane & 3) ^ ((row_ >> 1) & 3)) << 3);                                 \
            gload16(xbf + (size_t)(m0 + row_) * 512 + (t_) * 64 + (kk_) * 32 + kc_, Ad + ch_ * 512); \
        } }
#define STAGE_B(t_, kk_) {                                                                     \
        unsigned short* Bd = &Bs[(2 * (t_) + (kk_)) & 3][0];                                   \
        _Pragma("unroll")                                                                      \
        for (int i_ = 0; i_ < 2; i_++) {                                                       \
            int ch_ = wid * 2 + i_;                                                            \
            int row_ = ch_ * 16 + (lane >> 2);                                                 \
            int kc_ = (((lane & 3) ^ ((row_ >> 1) & 3)) << 3);                                 \
            gload16(wbf + (size_t)(n0 + row_) * 512 + (t_) * 64 + (kk_) * 32 + kc_, Bd + ch_ * 512); \
        } }
    // read: frag row r, logical k-group sb=lane>>4: elem = r*32 + ((sb ^ ((r>>1)&3))<<3)
#define RD_A(dst, t_, kk_, mih_, mi_) {                                                        \
        int r_ = wr * 128 + ((mih_) * 4 + (mi_)) * 16 + (lane & 15);                           \
        dst = *(const bf16x8*)&As[(2 * (t_) + (kk_)) & 3][r_ * 32 + ((((lane >> 4)) ^ ((r_ >> 1) & 3)) << 3)]; }
#define RD_B(dst, t_, kk_, ni_) {                                                              \
        int r_ = wc * 64 + (ni_) * 16 + (lane & 15);                                           \
        dst = *(const bf16x8*)&Bs[(2 * (t_) + (kk_)) & 3][r_ * 32 + ((((lane >> 4)) ^ ((r_ >> 1) & 3)) << 3)]; }

    // prologue: 12 loads
    STAGE_A(0, 0) STAGE_B(0, 0) STAGE_A(0, 1) STAGE_B(0, 1) STAGE_A(1, 0) STAGE_B(1, 0)

#pragma unroll
    for (int u = 0; u < 8; u++) {
        bf16x8 a[4], b[4];
        // ---- ph0: kk=0, mi 0-3 ----
        if (u < 7) { VMW8 } else { VMW4 }
        SBAR
        if (u + 1 < 8) STAGE_A(u + 1, 1)
#pragma unroll
        for (int mi = 0; mi < 4; mi++) RD_A(a[mi], u, 0, 0, mi)
#pragma unroll
        for (int ni = 0; ni < 4; ni++) RD_B(b[ni], u, 0, ni)
        LGKM0
        __builtin_amdgcn_s_setprio(1);
#pragma unroll
        for (int mi = 0; mi < 4; mi++)
#pragma unroll
            for (int ni = 0; ni < 4; ni++)
                acc[mi][ni] = __builtin_amdgcn_mfma_f32_16x16x32_bf16(a[mi], b[ni], acc[mi][ni], 0, 0, 0);
        __builtin_amdgcn_s_setprio(0);
        // ---- ph1: kk=0, mi 4-7 (b reused) ----
        if (u + 1 < 8) STAGE_B(u + 1, 1)
#pragma unroll
        for (int mi = 0; mi < 4; mi++) RD_A(a[mi], u, 0, 1, mi)
        LGKM0
        __builtin_amdgcn_s_setprio(1);
#pragma unroll
        for (int mi = 0; mi < 4; mi++)
#pragma unroll
            for (int ni = 0; ni < 4; ni++)
                acc[4 + mi][ni] = __builtin_amdgcn_mfma_f32_16x16x32_bf16(a[mi], b[ni], acc[4 + mi][ni], 0, 0, 0);
        __builtin_amdgcn_s_setprio(0);
        // ---- ph2: kk=1, mi 0-3 ----
        if (u < 7) { VMW8 } else { VMW0 }
        SBAR
        if (u + 2 < 8) STAGE_A(u + 2, 0)
#pragma unroll
        for (int mi = 0; mi < 4; mi++) RD_A(a[mi], u, 1, 0, mi)
#pragma unroll
        for (int ni = 0; ni < 4; ni++) RD_B(b[ni], u, 1, ni)
        LGKM0
        __builtin_amdgcn_s_setprio(1);
#pragma unroll
        for (int mi = 0; mi < 4; mi++)
#pragma unroll
            for (int ni = 0; ni < 4; ni++)
                acc[mi][ni] = __builtin_amdgcn_mfma_f32_16x16x32_bf16(a[mi], b[ni], acc[mi][ni], 0, 0, 0);
        __builtin_amdgcn_s_setprio(0);
        // ---- ph3: kk=1, mi 4-7 (b reused) ----
        if (u + 2 < 8) STAGE_B(u + 2, 0)
#pragma unroll
        for (int mi = 0; mi < 4; mi++) RD_A(a[mi], u, 1, 1, mi)
        LGKM0
        __builtin_amdgcn_s_setprio(1);
#pragma unroll
        for (int mi = 0; mi < 4; mi++)
#pragma unroll
            for (int ni = 0; ni < 4; ni++)
                acc[4 + mi][ni] = __builtin_amdgcn_mfma_f32_16x16x32_bf16(a[mi], b[ni], acc[4 + mi][ni], 0, 0, 0);
        __builtin_amdgcn_s_setprio(0);
    }
#undef STAGE_A
#undef STAGE_B
#undef RD_A
#undef RD_B

    // filter epilogue (pipeline fully drained)
#pragma unroll
    for (int mi = 0; mi < 8; mi++)
#pragma unroll
        for (int j = 0; j < 4; j++) {
            int pixel = m0 + wr * 128 + mi * 16 + (lane >> 4) * 4 + j;
            float tv = TN * sqrtf(thrS[pixel] * (1.0f / 512.0f));
#pragma unroll
            for (int ni = 0; ni < 4; ni++) {
                float v = acc[mi][ni][j];
                if (v >= tv) {
                    int lat = n0 + wc * 64 + ni * 16 + (lane & 15);
                    int slot = atomicAdd(&cnt[pixel], 1);
                    if (slot < CAP) cand[pixel * CAP + slot] = ((unsigned)f2bf(v) << 16) | (unsigned)lat;
                }
            }
        }
}

// ---- top-32 + decode fused: binary-search bf16 rank-32, exact seqFMA rescore pool, sort ----
__global__ __launch_bounds__(256) void k_topk(const float* __restrict__ xTf, const float* __restrict__ enc_w,
                                              const float* __restrict__ enc_b, const int* __restrict__ cnt,
                                              const unsigned int* __restrict__ cand,
                                              const unsigned short* __restrict__ dwT,
                                              const float* __restrict__ dec_b,
                                              float* __restrict__ out_acts, float* __restrict__ out_idx,
                                              float* __restrict__ out_sae, double* __restrict__ l2acc) {
    __shared__ __align__(16) float xrow[512];
    __shared__ unsigned long long skey2[SORT2];
    __shared__ int npool;
    __shared__ float sa[32];
    __shared__ int si[32];
    __shared__ double red[256];
    int p = blockIdx.x, tid = threadIdx.x;
    for (int i = tid; i < 512; i += 256) xrow[i] = xTf[(size_t)p * 512 + i];
    if (tid < SORT2) skey2[tid] = ~0ull;
    if (tid == 0) npool = 0;
    int c = cnt[p];
    if (c > CAP) c = CAP;
    unsigned int pk = (tid < c) ? cand[p * CAP + tid] : 0u;
    unsigned int bfb = pk >> 16;
    int lo = 0, hi = 65535;
    for (int it = 0; it < 16; it++) {
        int mid = (lo + hi + 1) >> 1;
        int n = __syncthreads_count(tid < c && bfb >= (unsigned)mid);
        if (n >= 32) lo = mid; else hi = mid - 1;
    }
    float pthr = bf2f((unsigned short)lo) - PMARG;
    __syncthreads();
    if (tid < c && bf2f((unsigned short)bfb) >= pthr) {
        int slot = atomicAdd(&npool, 1);
        if (slot < SORT2) {
            int lat = (int)(pk & 16383u);
            const float4* w4 = (const float4*)(enc_w + (size_t)lat * 512);
            const float4* x4 = (const float4*)xrow;
            float acc = 0.0f;
            for (int q = 0; q < 128; q++) {
                float4 w = w4[q];
                float4 xv = x4[q];
                acc = __fmaf_rn(xv.x, w.x, acc);
                acc = __fmaf_rn(xv.y, w.y, acc);
                acc = __fmaf_rn(xv.z, w.z, acc);
                acc = __fmaf_rn(xv.w, w.w, acc);
            }
            float pre = __fadd_rn(acc, enc_b[lat]);
            unsigned long long key;
            if (pre > 0.0f) {
                key = ((unsigned long long)(0xFFFFFFFFu - __float_as_uint(pre)) << 32) | (unsigned)lat;
            } else {
                key = 0xFFFFFFFF00000000ull | (unsigned)lat;
            }
            skey2[slot] = key;
        }
    }
    __syncthreads();
    for (int ks = 2; ks <= SORT2; ks <<= 1) {
        for (int jj = ks >> 1; jj > 0; jj >>= 1) {
            int i = tid;
            if (i < SORT2) {
                int ixj = i ^ jj;
                if (ixj > i) {
                    bool up = ((i & ks) == 0);
                    unsigned long long a = skey2[i], b2 = skey2[ixj];
                    if (up ? (a > b2) : (a < b2)) { skey2[i] = b2; skey2[ixj] = a; }
                }
            }
            __syncthreads();
        }
    }
    int b = p >> 8, hw = p & 255;
    if (tid < 32) {
        unsigned long long key = skey2[tid];
        unsigned int fb = 0xFFFFFFFFu - (unsigned int)(key >> 32);
        float act = fmaxf(__uint_as_float(fb), 0.0f);
        int lat = (int)(key & 16383u);
        sa[tid] = act;
        si[tid] = lat;
        out_acts[(size_t)b * 8192 + tid * 256 + hw] = act;
        out_idx[(size_t)b * 8192 + tid * 256 + hw] = (float)lat;
    }
    __syncthreads();
    float a0 = dec_b[tid], a1 = dec_b[tid + 256];
    for (int j = 0; j < 32; j++) {
        float a = sa[j];
        const unsigned short* r = dwT + (size_t)si[j] * 512;
        a0 += a * bf2f(r[tid]);
        a1 += a * bf2f(r[tid + 256]);
    }
    size_t o0 = (size_t)b * 131072 + (size_t)tid * 256 + hw;
    size_t o1 = o0 + 65536;
    out_sae[o0] = a0;
    out_sae[o1] = a1;
    float e0 = a0 - xrow[tid], e1 = a1 - xrow[tid + 256];
    red[tid] = (double)e0 * e0 + (double)e1 * e1;
    __syncthreads();
    for (int s = 128; s; s >>= 1) {
        if (tid < s) red[tid] += red[tid + s];
        __syncthreads();
    }
    if (tid == 0) atomicAdd(l2acc, red[0]);
}

// ---------------- finalize fvu ----------------
__global__ __launch_bounds__(256) void k_fin(const double* __restrict__ l2, const double* __restrict__ S,
                                             const double* __restrict__ Q, float* __restrict__ out_sc) {
    __shared__ double red[256];
    int tid = threadIdx.x;
    double tv = 0;
    for (int c = tid; c < 512; c += 256) tv += Q[c] - S[c] * S[c] * (1.0 / 4096.0);
    red[tid] = tv;
    __syncthreads();
    for (int s = 128; s; s >>= 1) {
        if (tid < s) red[tid] += red[tid + s];
        __syncthreads();
    }
    if (tid == 0) {
        double fvu = l2[0] / red[0];
        out_sc[0] = (float)fvu;
        out_sc[1] = 0.0f;
        out_sc[2] = 0.0f;
    }
}

extern "C" void kernel_launch(void* const* d_in, const int* in_sizes, int n_in,
                              void* d_out, int out_size, void* d_ws, size_t ws_size,
                              hipStream_t stream) {
    const float* x = (const float*)d_in[0];
    const float* enc_w = (const float*)d_in[1];
    const float* enc_b = (const float*)d_in[2];
    const float* dec_w = (const float*)d_in[3];
    const float* dec_b = (const float*)d_in[4];
    (void)in_sizes; (void)n_in; (void)out_size; (void)ws_size;

    char* ws = (char*)d_ws;
    float* xTf = (float*)ws;                                  //  8 MB
    unsigned short* xTb = (unsigned short*)(ws + 8388608);    //  4 MB
    unsigned short* ewb = (unsigned short*)(ws + 12582912);   // 16 MB
    unsigned short* dwT = (unsigned short*)(ws + 29360128);   // 16 MB
    unsigned int* cand = (unsigned int*)(ws + 46137344);      //  3.67 MB (4096*224*4)
    int* cnt = (int*)(ws + 49807360);                         // 16 KB
    float* thrS = (float*)(ws + 49823744);                    // 16 KB
    double* S = (double*)(ws + 49840128);                     //  4 KB
    double* Q = (double*)(ws + 49844224);                     //  4 KB
    double* l2 = (double*)(ws + 49848320);                    //  8 B

    float* out = (float*)d_out;   // reference outputs are float32
    float* out_sae = out;
    float* out_acts = out + 2097152;
    float* out_idx = out + 2228224;
    float* out_sc = out + 2359296;

    hipMemsetAsync(cnt, 0, 16384 + 16384 + 4096 + 4096 + 8, stream);

    t1_x<<<dim3(8, 4, 16), 256, 0, stream>>>(x, xTf, xTb, thrS, S, Q);
    t2_encw<<<4096, 256, 0, stream>>>(enc_w, ewb);
    t3_decw<<<dim3(256, 8), 256, 0, stream>>>(dec_w, dwT);
    k_gemm<<<dim3(64, 16), 512, 0, stream>>>(xTb, ewb, thrS, cnt, cand);
    k_topk<<<4096, 256, 0, stream>>>(xTf, enc_w, enc_b, cnt, cand, dwT, dec_b,
                                     out_acts, out_idx, out_sae, l2);
    k_fin<<<1, 256, 0, stream>>>(l2, S, Q, out_sc);
}

// Round 15
// 326.543 us; speedup vs baseline: 1.0882x; 1.0739x over previous
//
#include <hip/hip_runtime.h>
#include <stdint.h>

typedef __attribute__((ext_vector_type(4))) int i32x4;

#define TN 2.45f          // normalized filter threshold (units of s_p)
#define PMARG 0.16f       // exact-rescore pool margin below approx rank-32
#define CAP 224
#define SORT2 128

__device__ inline float bf2f(unsigned short u) { return __uint_as_float(((unsigned int)u) << 16); }
__device__ inline unsigned short f2bf(float f) {
    unsigned int x = __float_as_uint(f);
    return (unsigned short)((x + 0x7FFFu + ((x >> 16) & 1u)) >> 16);  // RNE
}

template <typename T>
__device__ inline void gload16(const T* g, T* l) {
    __builtin_amdgcn_global_load_lds((const __attribute__((address_space(1))) void*)g,
                                     (__attribute__((address_space(3))) void*)l, 16, 0, 0);
}

// ---- T1: x [16][512][256] -> xT [4096][512] f32 + ||x_p||^2 + per-channel S/Q ----
__global__ __launch_bounds__(256) void t1_x(const float* __restrict__ x, float* __restrict__ xTf,
                                            float* __restrict__ thrS,
                                            double* __restrict__ S, double* __restrict__ Q) {
    __shared__ float tile[64][65];
    int b = blockIdx.z, c0 = blockIdx.x * 64, hw0 = blockIdx.y * 64;
    int tid = threadIdx.x, g = tid >> 6, ln = tid & 63;
    for (int i = 0; i < 16; i++) {
        int cl = g * 16 + i;
        tile[cl][ln] = x[(size_t)(b * 512 + c0 + cl) * 256 + hw0 + ln];
    }
    __syncthreads();
    float s1 = 0.0f, s2 = 0.0f;
    for (int i = 0; i < 16; i++) {
        int hl = g * 16 + i;
        float v = tile[ln][hl];
        xTf[(size_t)(b * 256 + hw0 + hl) * 512 + c0 + ln] = v;
        s1 += v;
        s2 += v * v;
        float s = v * v;
        for (int off = 32; off; off >>= 1) s += __shfl_down(s, off, 64);
        if (ln == 0) atomicAdd(&thrS[b * 256 + hw0 + hl], s);
    }
    atomicAdd(&S[c0 + ln], (double)s1);
    atomicAdd(&Q[c0 + ln], (double)s2);
}

// ---- quantize a [N][512] f32 row-major matrix to int8 with per-row max scale ----
// one wave per row; lane holds 8 consecutive floats
__device__ inline void quant_row(const float* __restrict__ src, signed char* __restrict__ dst,
                                 float* __restrict__ scale, int row, int lane) {
    const float4* s4 = (const float4*)(src + (size_t)row * 512);
    float4 a = s4[lane * 2], b = s4[lane * 2 + 1];
    float m = fmaxf(fmaxf(fmaxf(fabsf(a.x), fabsf(a.y)), fmaxf(fabsf(a.z), fabsf(a.w))),
                    fmaxf(fmaxf(fabsf(b.x), fabsf(b.y)), fmaxf(fabsf(b.z), fabsf(b.w))));
    for (int off = 32; off; off >>= 1) m = fmaxf(m, __shfl_xor(m, off, 64));
    m = fmaxf(m, 1e-20f);
    float inv = 127.0f / m;
    int q0 = __float2int_rn(a.x * inv), q1 = __float2int_rn(a.y * inv);
    int q2 = __float2int_rn(a.z * inv), q3 = __float2int_rn(a.w * inv);
    int q4 = __float2int_rn(b.x * inv), q5 = __float2int_rn(b.y * inv);
    int q6 = __float2int_rn(b.z * inv), q7 = __float2int_rn(b.w * inv);
    unsigned int w0 = (q0 & 255) | ((q1 & 255) << 8) | ((q2 & 255) << 16) | ((unsigned)(q3 & 255) << 24);
    unsigned int w1 = (q4 & 255) | ((q5 & 255) << 8) | ((q6 & 255) << 16) | ((unsigned)(q7 & 255) << 24);
    *(uint2*)(dst + (size_t)row * 512 + lane * 8) = make_uint2(w0, w1);
    if (lane == 0) scale[row] = m * (1.0f / 127.0f);
}

__global__ __launch_bounds__(256) void k_qx(const float* __restrict__ xTf, signed char* __restrict__ xq,
                                            float* __restrict__ sx) {
    quant_row(xTf, xq, sx, blockIdx.x * 4 + (threadIdx.x >> 6), threadIdx.x & 63);
}
__global__ __launch_bounds__(256) void k_qw(const float* __restrict__ w, signed char* __restrict__ wq,
                                            float* __restrict__ sw) {
    quant_row(w, wq, sw, blockIdx.x * 4 + (threadIdx.x >> 6), threadIdx.x & 63);
}

// ---------------- T3: dec_w [512][16384] -> dec_wT [16384][512] bf16 ----------------
__global__ __launch_bounds__(256) void t3_decw(const float* __restrict__ w, unsigned short* __restrict__ wT) {
    __shared__ float tile[64][65];
    int l0 = blockIdx.x * 64, d0 = blockIdx.y * 64;
    int tid = threadIdx.x, g = tid >> 6, ln = tid & 63;
    for (int i = 0; i < 16; i++) {
        int dl = g * 16 + i;
        tile[dl][ln] = w[(size_t)(d0 + dl) * 16384 + l0 + ln];
    }
    __syncthreads();
    for (int i = 0; i < 16; i++) {
        int ll = g * 16 + i;
        wT[(size_t)(l0 + ll) * 512 + d0 + ln] = f2bf(tile[ln][ll]);
    }
}

// ---- GEMM int8: 128x256 tile, BK=128 (4 K-tiles), mfma_i32_16x16x64_i8, 3-buf depth-2
//      counted vmcnt(6) (R8/R12-proven pipeline), XOR swizzle, XCD swizzle ----
// LDS rows are 128 i8 = 128B = 32 banks: swizzle 16B-slot ^= (row&7) -> 2-way (free).
#define SBAR                                   \
    __builtin_amdgcn_sched_barrier(0);         \
    __builtin_amdgcn_s_barrier();              \
    __builtin_amdgcn_sched_barrier(0);
#define VMW6 { asm volatile("s_waitcnt vmcnt(6)" ::: "memory"); __builtin_amdgcn_sched_barrier(0); }
#define VMW0 { asm volatile("s_waitcnt vmcnt(0)" ::: "memory"); __builtin_amdgcn_sched_barrier(0); }

__global__ __launch_bounds__(512) void k_gemm(const signed char* __restrict__ xq,
                                              const signed char* __restrict__ wq,
                                              const float* __restrict__ sx, const float* __restrict__ sw,
                                              const float* __restrict__ thrS,
                                              int* __restrict__ cnt, unsigned int* __restrict__ cand) {
    __shared__ __align__(16) signed char As[3][128 * 128];  // 3 x 16KB
    __shared__ __align__(16) signed char Bs[3][256 * 128];  // 3 x 32KB  (tot 144KB)
    int tid = threadIdx.x, wid = tid >> 6, lane = tid & 63;

    // XCD swizzle (bijective, 2048 blocks): each XCD owns 8 consecutive n-panels
    int lin = blockIdx.x + blockIdx.y * gridDim.x;   // grid (64 n, 32 m)
    int swz = (lin & 7) * 256 + (lin >> 3);
    int bx = swz >> 5;          // n-block 0..63
    int by = swz & 31;          // m-block 0..31
    int m0 = by * 128, n0 = bx * 256;
    int wr = wid >> 2, wc = wid & 3;   // 2(M) x 4(N); per-wave 64x64

    i32x4 acc[4][4];
#pragma unroll
    for (int mi = 0; mi < 4; mi++)
#pragma unroll
        for (int ni = 0; ni < 4; ni++)
#pragma unroll
            for (int j = 0; j < 4; j++) acc[mi][ni][j] = 0;

    // staging: chunk = 8 rows x 128B = 1KB; lane -> row lane>>3, 16B-slot lane&7,
    // source slot pre-swizzled by row (involution; read side XORs r&7)
    int srow = lane >> 3;
    int scol = (((lane & 7) ^ (lane >> 3)) << 4);   // (lane>>3)&7 == lane>>3 (<8)

#define STAGE(bufi, kt)                                                                           \
    {                                                                                             \
        signed char* Ad = &As[bufi][0];                                                           \
        signed char* Bd = &Bs[bufi][0];                                                           \
        _Pragma("unroll")                                                                         \
        for (int i_ = 0; i_ < 2; i_++) {                                                          \
            int ch_ = wid * 2 + i_;                                                               \
            gload16(xq + (size_t)(m0 + ch_ * 8 + srow) * 512 + (kt) + scol, Ad + ch_ * 1024);     \
        }                                                                                         \
        _Pragma("unroll")                                                                         \
        for (int i_ = 0; i_ < 4; i_++) {                                                          \
            int ch_ = wid * 4 + i_;                                                               \
            gload16(wq + (size_t)(n0 + ch_ * 8 + srow) * 512 + (kt) + scol, Bd + ch_ * 1024);     \
        }                                                                                         \
    }

    STAGE(0, 0)
    STAGE(1, 128)    // depth-2: 12 loads/wave in flight
    int cur = 0;
#pragma unroll
    for (int t = 0; t < 4; t++) {
        if (t < 3) VMW6      // tile t landed; tile t+1's 6 loads stay in flight
        else VMW0
        SBAR                  // tile t visible; readers of buffer (t+2)%3 retired
        if (t < 2) STAGE((cur + 2) % 3, (t + 2) * 128)
        const signed char* Ac = &As[cur][0];
        const signed char* Bc = &Bs[cur][0];
#pragma unroll
        for (int kk = 0; kk < 2; kk++) {      // two K=64 chunks per tile
            i32x4 a[4], b[4];
#pragma unroll
            for (int mi = 0; mi < 4; mi++) {
                int r = wr * 64 + mi * 16 + (lane & 15);
                int slot = (kk * 4 + (lane >> 4)) ^ (r & 7);
                a[mi] = *(const i32x4*)&Ac[r * 128 + slot * 16];
            }
#pragma unroll
            for (int ni = 0; ni < 4; ni++) {
                int r = wc * 64 + ni * 16 + (lane & 15);
                int slot = (kk * 4 + (lane >> 4)) ^ (r & 7);
                b[ni] = *(const i32x4*)&Bc[r * 128 + slot * 16];
            }
#pragma unroll
            for (int mi = 0; mi < 4; mi++)
#pragma unroll
                for (int ni = 0; ni < 4; ni++)
                    acc[mi][ni] = __builtin_amdgcn_mfma_i32_16x16x64_i8(a[mi], b[ni], acc[mi][ni], 0, 0, 0);
        }
        cur = (cur + 1) % 3;
    }
#undef STAGE

    // filter epilogue: v = dot * sx[pixel] * sw[lat];  C/D row=(lane>>4)*4+j, col=lane&15
    float swl[4];
#pragma unroll
    for (int ni = 0; ni < 4; ni++) swl[ni] = sw[n0 + wc * 64 + ni * 16 + (lane & 15)];
#pragma unroll
    for (int mi = 0; mi < 4; mi++)
#pragma unroll
        for (int j = 0; j < 4; j++) {
            int pixel = m0 + wr * 64 + mi * 16 + (lane >> 4) * 4 + j;
            float tv = TN * sqrtf(thrS[pixel] * (1.0f / 512.0f));
            float sxp = sx[pixel];
#pragma unroll
            for (int ni = 0; ni < 4; ni++) {
                float v = (float)acc[mi][ni][j] * (sxp * swl[ni]);
                if (v >= tv) {
                    int lat = n0 + wc * 64 + ni * 16 + (lane & 15);
                    int slot = atomicAdd(&cnt[pixel], 1);
                    if (slot < CAP) cand[pixel * CAP + slot] = ((unsigned)f2bf(v) << 16) | (unsigned)lat;
                }
            }
        }
}

// ---- top-32 + decode fused: binary-search approx rank-32, exact seqFMA rescore pool, sort ----
__global__ __launch_bounds__(256) void k_topk(const float* __restrict__ xTf, const float* __restrict__ enc_w,
                                              const float* __restrict__ enc_b, const int* __restrict__ cnt,
                                              const unsigned int* __restrict__ cand,
                                              const unsigned short* __restrict__ dwT,
                                              const float* __restrict__ dec_b,
                                              float* __restrict__ out_acts, float* __restrict__ out_idx,
                                              float* __restrict__ out_sae, double* __restrict__ l2acc) {
    __shared__ __align__(16) float xrow[512];
    __shared__ unsigned long long skey2[SORT2];
    __shared__ int npool;
    __shared__ float sa[32];
    __shared__ int si[32];
    __shared__ double red[256];
    int p = blockIdx.x, tid = threadIdx.x;
    for (int i = tid; i < 512; i += 256) xrow[i] = xTf[(size_t)p * 512 + i];
    if (tid < SORT2) skey2[tid] = ~0ull;
    if (tid == 0) npool = 0;
    int c = cnt[p];
    if (c > CAP) c = CAP;
    unsigned int pk = (tid < c) ? cand[p * CAP + tid] : 0u;
    unsigned int bfb = pk >> 16;
    int lo = 0, hi = 65535;
    for (int it = 0; it < 16; it++) {
        int mid = (lo + hi + 1) >> 1;
        int n = __syncthreads_count(tid < c && bfb >= (unsigned)mid);
        if (n >= 32) lo = mid; else hi = mid - 1;
    }
    float pthr = bf2f((unsigned short)lo) - PMARG;
    __syncthreads();
    if (tid < c && bf2f((unsigned short)bfb) >= pthr) {
        int slot = atomicAdd(&npool, 1);
        if (slot < SORT2) {
            int lat = (int)(pk & 16383u);
            const float4* w4 = (const float4*)(enc_w + (size_t)lat * 512);
            const float4* x4 = (const float4*)xrow;
            float acc = 0.0f;
            for (int q = 0; q < 128; q++) {
                float4 w = w4[q];
                float4 xv = x4[q];
                acc = __fmaf_rn(xv.x, w.x, acc);
                acc = __fmaf_rn(xv.y, w.y, acc);
                acc = __fmaf_rn(xv.z, w.z, acc);
                acc = __fmaf_rn(xv.w, w.w, acc);
            }
            float pre = __fadd_rn(acc, enc_b[lat]);
            unsigned long long key;
            if (pre > 0.0f) {
                key = ((unsigned long long)(0xFFFFFFFFu - __float_as_uint(pre)) << 32) | (unsigned)lat;
            } else {
                key = 0xFFFFFFFF00000000ull | (unsigned)lat;
            }
            skey2[slot] = key;
        }
    }
    __syncthreads();
    for (int ks = 2; ks <= SORT2; ks <<= 1) {
        for (int jj = ks >> 1; jj > 0; jj >>= 1) {
            int i = tid;
            if (i < SORT2) {
                int ixj = i ^ jj;
                if (ixj > i) {
                    bool up = ((i & ks) == 0);
                    unsigned long long a = skey2[i], b2 = skey2[ixj];
                    if (up ? (a > b2) : (a < b2)) { skey2[i] = b2; skey2[ixj] = a; }
                }
            }
            __syncthreads();
        }
    }
    int b = p >> 8, hw = p & 255;
    if (tid < 32) {
        unsigned long long key = skey2[tid];
        unsigned int fb = 0xFFFFFFFFu - (unsigned int)(key >> 32);
        float act = fmaxf(__uint_as_float(fb), 0.0f);
        int lat = (int)(key & 16383u);
        sa[tid] = act;
        si[tid] = lat;
        out_acts[(size_t)b * 8192 + tid * 256 + hw] = act;
        out_idx[(size_t)b * 8192 + tid * 256 + hw] = (float)lat;
    }
    __syncthreads();
    float a0 = dec_b[tid], a1 = dec_b[tid + 256];
    for (int j = 0; j < 32; j++) {
        float a = sa[j];
        const unsigned short* r = dwT + (size_t)si[j] * 512;
        a0 += a * bf2f(r[tid]);
        a1 += a * bf2f(r[tid + 256]);
    }
    size_t o0 = (size_t)b * 131072 + (size_t)tid * 256 + hw;
    size_t o1 = o0 + 65536;
    out_sae[o0] = a0;
    out_sae[o1] = a1;
    float e0 = a0 - xrow[tid], e1 = a1 - xrow[tid + 256];
    red[tid] = (double)e0 * e0 + (double)e1 * e1;
    __syncthreads();
    for (int s = 128; s; s >>= 1) {
        if (tid < s) red[tid] += red[tid + s];
        __syncthreads();
    }
    if (tid == 0) atomicAdd(l2acc, red[0]);
}

// ---------------- finalize fvu ----------------
__global__ __launch_bounds__(256) void k_fin(const double* __restrict__ l2, const double* __restrict__ S,
                                             const double* __restrict__ Q, float* __restrict__ out_sc) {
    __shared__ double red[256];
    int tid = threadIdx.x;
    double tv = 0;
    for (int c = tid; c < 512; c += 256) tv += Q[c] - S[c] * S[c] * (1.0 / 4096.0);
    red[tid] = tv;
    __syncthreads();
    for (int s = 128; s; s >>= 1) {
        if (tid < s) red[tid] += red[tid + s];
        __syncthreads();
    }
    if (tid == 0) {
        double fvu = l2[0] / red[0];
        out_sc[0] = (float)fvu;
        out_sc[1] = 0.0f;
        out_sc[2] = 0.0f;
    }
}

extern "C" void kernel_launch(void* const* d_in, const int* in_sizes, int n_in,
                              void* d_out, int out_size, void* d_ws, size_t ws_size,
                              hipStream_t stream) {
    const float* x = (const float*)d_in[0];
    const float* enc_w = (const float*)d_in[1];
    const float* enc_b = (const float*)d_in[2];
    const float* dec_w = (const float*)d_in[3];
    const float* dec_b = (const float*)d_in[4];
    (void)in_sizes; (void)n_in; (void)out_size; (void)ws_size;

    char* ws = (char*)d_ws;
    float* xTf = (float*)ws;                                   //  8 MB
    signed char* xq = (signed char*)(ws + 8388608);            //  2 MB
    signed char* wq = (signed char*)(ws + 10485760);           //  8 MB
    unsigned short* dwT = (unsigned short*)(ws + 18874368);    // 16 MB
    unsigned int* cand = (unsigned int*)(ws + 35651584);       //  3.67 MB (4096*224*4)
    // contiguous zero-init region: cnt | thrS | S | Q | l2
    int* cnt = (int*)(ws + 39321600);                          // 16 KB
    float* thrS = (float*)(ws + 39337984);                     // 16 KB
    double* S = (double*)(ws + 39354368);                      //  4 KB
    double* Q = (double*)(ws + 39358464);                      //  4 KB
    double* l2 = (double*)(ws + 39362560);                     //  8 B
    float* sx = (float*)(ws + 39366656);                       // 16 KB
    float* sw = (float*)(ws + 39383040);                       // 64 KB

    float* out = (float*)d_out;   // reference outputs are float32
    float* out_sae = out;
    float* out_acts = out + 2097152;
    float* out_idx = out + 2228224;
    float* out_sc = out + 2359296;

    hipMemsetAsync(cnt, 0, 16384 + 16384 + 4096 + 4096 + 8, stream);

    t1_x<<<dim3(8, 4, 16), 256, 0, stream>>>(x, xTf, thrS, S, Q);
    k_qx<<<1024, 256, 0, stream>>>(xTf, xq, sx);
    k_qw<<<4096, 256, 0, stream>>>(enc_w, wq, sw);
    t3_decw<<<dim3(256, 8), 256, 0, stream>>>(dec_w, dwT);
    k_gemm<<<dim3(64, 32), 512, 0, stream>>>(xq, wq, sx, sw, thrS, cnt, cand);
    k_topk<<<4096, 256, 0, stream>>>(xTf, enc_w, enc_b, cnt, cand, dwT, dec_b,
                                     out_acts, out_idx, out_sae, l2);
    k_fin<<<1, 256, 0, stream>>>(l2, S, Q, out_sc);
}

// Round 16
// 295.514 us; speedup vs baseline: 1.2025x; 1.1050x over previous
//
#include <hip/hip_runtime.h>
#include <stdint.h>

typedef __attribute__((ext_vector_type(4))) int i32x4;

#define TN 2.45f          // normalized filter threshold (units of s_p)
#define PMARG 0.16f       // exact-rescore pool margin below approx rank-32
#define CAP 224
#define SORT2 128

__device__ inline float bf2f(unsigned short u) { return __uint_as_float(((unsigned int)u) << 16); }
__device__ inline unsigned short f2bf(float f) {
    unsigned int x = __float_as_uint(f);
    return (unsigned short)((x + 0x7FFFu + ((x >> 16) & 1u)) >> 16);  // RNE
}

template <typename T>
__device__ inline void gload16(const T* g, T* l) {
    __builtin_amdgcn_global_load_lds((const __attribute__((address_space(1))) void*)g,
                                     (__attribute__((address_space(3))) void*)l, 16, 0, 0);
}

// ---- T1: x [16][512][256] -> xT [4096][512] f32 + ||x_p||^2 + per-channel S/Q ----
__global__ __launch_bounds__(256) void t1_x(const float* __restrict__ x, float* __restrict__ xTf,
                                            float* __restrict__ thrS,
                                            double* __restrict__ S, double* __restrict__ Q) {
    __shared__ float tile[64][65];
    int b = blockIdx.z, c0 = blockIdx.x * 64, hw0 = blockIdx.y * 64;
    int tid = threadIdx.x, g = tid >> 6, ln = tid & 63;
    for (int i = 0; i < 16; i++) {
        int cl = g * 16 + i;
        tile[cl][ln] = x[(size_t)(b * 512 + c0 + cl) * 256 + hw0 + ln];
    }
    __syncthreads();
    float s1 = 0.0f, s2 = 0.0f;
    for (int i = 0; i < 16; i++) {
        int hl = g * 16 + i;
        float v = tile[ln][hl];
        xTf[(size_t)(b * 256 + hw0 + hl) * 512 + c0 + ln] = v;
        s1 += v;
        s2 += v * v;
        float s = v * v;
        for (int off = 32; off; off >>= 1) s += __shfl_down(s, off, 64);
        if (ln == 0) atomicAdd(&thrS[b * 256 + hw0 + hl], s);
    }
    atomicAdd(&S[c0 + ln], (double)s1);
    atomicAdd(&Q[c0 + ln], (double)s2);
}

// ---- quantize a [N][512] f32 row-major matrix to int8 with per-row max scale ----
__device__ inline void quant_row(const float* __restrict__ src, signed char* __restrict__ dst,
                                 float* __restrict__ scale, int row, int lane) {
    const float4* s4 = (const float4*)(src + (size_t)row * 512);
    float4 a = s4[lane * 2], b = s4[lane * 2 + 1];
    float m = fmaxf(fmaxf(fmaxf(fabsf(a.x), fabsf(a.y)), fmaxf(fabsf(a.z), fabsf(a.w))),
                    fmaxf(fmaxf(fabsf(b.x), fabsf(b.y)), fmaxf(fabsf(b.z), fabsf(b.w))));
    for (int off = 32; off; off >>= 1) m = fmaxf(m, __shfl_xor(m, off, 64));
    m = fmaxf(m, 1e-20f);
    float inv = 127.0f / m;
    int q0 = __float2int_rn(a.x * inv), q1 = __float2int_rn(a.y * inv);
    int q2 = __float2int_rn(a.z * inv), q3 = __float2int_rn(a.w * inv);
    int q4 = __float2int_rn(b.x * inv), q5 = __float2int_rn(b.y * inv);
    int q6 = __float2int_rn(b.z * inv), q7 = __float2int_rn(b.w * inv);
    unsigned int w0 = (q0 & 255) | ((q1 & 255) << 8) | ((q2 & 255) << 16) | ((unsigned)(q3 & 255) << 24);
    unsigned int w1 = (q4 & 255) | ((q5 & 255) << 8) | ((q6 & 255) << 16) | ((unsigned)(q7 & 255) << 24);
    *(uint2*)(dst + (size_t)row * 512 + lane * 8) = make_uint2(w0, w1);
    if (lane == 0) scale[row] = m * (1.0f / 127.0f);
}

__global__ __launch_bounds__(256) void k_qx(const float* __restrict__ xTf, signed char* __restrict__ xq,
                                            float* __restrict__ sx) {
    quant_row(xTf, xq, sx, blockIdx.x * 4 + (threadIdx.x >> 6), threadIdx.x & 63);
}
__global__ __launch_bounds__(256) void k_qw(const float* __restrict__ w, signed char* __restrict__ wq,
                                            float* __restrict__ sw) {
    quant_row(w, wq, sw, blockIdx.x * 4 + (threadIdx.x >> 6), threadIdx.x & 63);
}

// ---------------- T3: dec_w [512][16384] -> dec_wT [16384][512] bf16 ----------------
__global__ __launch_bounds__(256) void t3_decw(const float* __restrict__ w, unsigned short* __restrict__ wT) {
    __shared__ float tile[64][65];
    int l0 = blockIdx.x * 64, d0 = blockIdx.y * 64;
    int tid = threadIdx.x, g = tid >> 6, ln = tid & 63;
    for (int i = 0; i < 16; i++) {
        int dl = g * 16 + i;
        tile[dl][ln] = w[(size_t)(d0 + dl) * 16384 + l0 + ln];
    }
    __syncthreads();
    for (int i = 0; i < 16; i++) {
        int ll = g * 16 + i;
        wT[(size_t)(l0 + ll) * 512 + d0 + ln] = f2bf(tile[ln][ll]);
    }
}

// ---- GEMM int8: 128x128 tile, BK=64, 256 thr, 2-buf 32KB LDS -> 4-5 blocks/CU (TLP!),
//      plain 2-phase prefetch loop (R6-proven), XOR swizzle for 64B rows, XCD swizzle ----
// LDS row = 64B = 4 x 16B slots; read slot_phys = slot_log ^ ((r>>1)&3): rows {r, r+8}
// share banks -> 2-way (free, m136). Staging: linear dest; source col pre-swizzled.
__global__ __launch_bounds__(256) void k_gemm(const signed char* __restrict__ xq,
                                              const signed char* __restrict__ wq,
                                              const float* __restrict__ sx, const float* __restrict__ sw,
                                              const float* __restrict__ thrS,
                                              int* __restrict__ cnt, unsigned int* __restrict__ cand) {
    __shared__ __align__(16) signed char As[2][128 * 64];  // 2 x 8KB
    __shared__ __align__(16) signed char Bs[2][128 * 64];  // 2 x 8KB  (tot 32KB)
    int tid = threadIdx.x, wid = tid >> 6, lane = tid & 63;

    // XCD swizzle (bijective, 4096 blocks = 8 x 512): XCD owns 16 n-blocks (1MB B slice)
    int lin = blockIdx.x + blockIdx.y * gridDim.x;   // grid (128 n, 32 m)
    int swz = (lin & 7) * 512 + (lin >> 3);
    int bx = swz >> 5;          // n-block 0..127
    int by = swz & 31;          // m-block 0..31
    int m0 = by * 128, n0 = bx * 128;
    int wr = wid >> 1, wc = wid & 1;   // 2x2 waves; per-wave 64x64

    i32x4 acc[4][4];
#pragma unroll
    for (int mi = 0; mi < 4; mi++)
#pragma unroll
        for (int ni = 0; ni < 4; ni++)
#pragma unroll
            for (int j = 0; j < 4; j++) acc[mi][ni][j] = 0;

    // staging: chunk = 16 rows x 64B = 1KB; A and B each have 8 chunks; wave stages 2 of each.
    // lane -> row = ch*16 + (lane>>2), dest slot = lane&3 (linear); source slot pre-swizzled.
    int srow = lane >> 2;                 // 0..15 within chunk

#define STAGE(bufi, kt)                                                                            \
    {                                                                                              \
        signed char* Ad = &As[bufi][0];                                                            \
        signed char* Bd = &Bs[bufi][0];                                                            \
        _Pragma("unroll")                                                                          \
        for (int i_ = 0; i_ < 2; i_++) {                                                           \
            int ch_ = wid * 2 + i_;                                                                \
            int row_ = ch_ * 16 + srow;                                                            \
            int sc_ = (((lane & 3) ^ ((row_ >> 1) & 3)) << 4);                                     \
            gload16(xq + (size_t)(m0 + row_) * 512 + (kt) + sc_, Ad + ch_ * 1024);                 \
            gload16(wq + (size_t)(n0 + row_) * 512 + (kt) + sc_, Bd + ch_ * 1024);                 \
        }                                                                                          \
    }

    STAGE(0, 0)
    __syncthreads();   // tile 0 ready (vmcnt+lgkm drained by barrier semantics)
    int cur = 0;
#pragma unroll
    for (int t = 0; t < 8; t++) {
        if (t < 7) STAGE(cur ^ 1, (t + 1) * 64)   // prefetch next tile under compute
        const signed char* Ac = &As[cur][0];
        const signed char* Bc = &Bs[cur][0];
        i32x4 a[4], b[4];
#pragma unroll
        for (int mi = 0; mi < 4; mi++) {
            int r = wr * 64 + mi * 16 + (lane & 15);
            int slot = (lane >> 4) ^ ((r >> 1) & 3);
            a[mi] = *(const i32x4*)&Ac[r * 64 + slot * 16];
        }
#pragma unroll
        for (int ni = 0; ni < 4; ni++) {
            int r = wc * 64 + ni * 16 + (lane & 15);
            int slot = (lane >> 4) ^ ((r >> 1) & 3);
            b[ni] = *(const i32x4*)&Bc[r * 64 + slot * 16];
        }
#pragma unroll
        for (int mi = 0; mi < 4; mi++)
#pragma unroll
            for (int ni = 0; ni < 4; ni++)
                acc[mi][ni] = __builtin_amdgcn_mfma_i32_16x16x64_i8(a[mi], b[ni], acc[mi][ni], 0, 0, 0);
        __syncthreads();   // prefetch landed; readers of cur retired
        cur ^= 1;
    }
#undef STAGE

    // filter epilogue: v = dot * sx[pixel] * sw[lat];  C/D row=(lane>>4)*4+j, col=lane&15
    float swl[4];
#pragma unroll
    for (int ni = 0; ni < 4; ni++) swl[ni] = sw[n0 + wc * 64 + ni * 16 + (lane & 15)];
#pragma unroll
    for (int mi = 0; mi < 4; mi++)
#pragma unroll
        for (int j = 0; j < 4; j++) {
            int pixel = m0 + wr * 64 + mi * 16 + (lane >> 4) * 4 + j;
            float tv = TN * sqrtf(thrS[pixel] * (1.0f / 512.0f));
            float sxp = sx[pixel];
#pragma unroll
            for (int ni = 0; ni < 4; ni++) {
                float v = (float)acc[mi][ni][j] * (sxp * swl[ni]);
                if (v >= tv) {
                    int lat = n0 + wc * 64 + ni * 16 + (lane & 15);
                    int slot = atomicAdd(&cnt[pixel], 1);
                    if (slot < CAP) cand[pixel * CAP + slot] = ((unsigned)f2bf(v) << 16) | (unsigned)lat;
                }
            }
        }
}

// ---- top-32 + decode fused: binary-search approx rank-32, exact seqFMA rescore pool, sort ----
__global__ __launch_bounds__(256) void k_topk(const float* __restrict__ xTf, const float* __restrict__ enc_w,
                                              const float* __restrict__ enc_b, const int* __restrict__ cnt,
                                              const unsigned int* __restrict__ cand,
                                              const unsigned short* __restrict__ dwT,
                                              const float* __restrict__ dec_b,
                                              float* __restrict__ out_acts, float* __restrict__ out_idx,
                                              float* __restrict__ out_sae, double* __restrict__ l2acc) {
    __shared__ __align__(16) float xrow[512];
    __shared__ unsigned long long skey2[SORT2];
    __shared__ int npool;
    __shared__ float sa[32];
    __shared__ int si[32];
    __shared__ double red[256];
    int p = blockIdx.x, tid = threadIdx.x;
    for (int i = tid; i < 512; i += 256) xrow[i] = xTf[(size_t)p * 512 + i];
    if (tid < SORT2) skey2[tid] = ~0ull;
    if (tid == 0) npool = 0;
    int c = cnt[p];
    if (c > CAP) c = CAP;
    unsigned int pk = (tid < c) ? cand[p * CAP + tid] : 0u;
    unsigned int bfb = pk >> 16;
    int lo = 0, hi = 65535;
    for (int it = 0; it < 16; it++) {
        int mid = (lo + hi + 1) >> 1;
        int n = __syncthreads_count(tid < c && bfb >= (unsigned)mid);
        if (n >= 32) lo = mid; else hi = mid - 1;
    }
    float pthr = bf2f((unsigned short)lo) - PMARG;
    __syncthreads();
    if (tid < c && bf2f((unsigned short)bfb) >= pthr) {
        int slot = atomicAdd(&npool, 1);
        if (slot < SORT2) {
            int lat = (int)(pk & 16383u);
            const float4* w4 = (const float4*)(enc_w + (size_t)lat * 512);
            const float4* x4 = (const float4*)xrow;
            float acc = 0.0f;
            for (int q = 0; q < 128; q++) {
                float4 w = w4[q];
                float4 xv = x4[q];
                acc = __fmaf_rn(xv.x, w.x, acc);
                acc = __fmaf_rn(xv.y, w.y, acc);
                acc = __fmaf_rn(xv.z, w.z, acc);
                acc = __fmaf_rn(xv.w, w.w, acc);
            }
            float pre = __fadd_rn(acc, enc_b[lat]);
            unsigned long long key;
            if (pre > 0.0f) {
                key = ((unsigned long long)(0xFFFFFFFFu - __float_as_uint(pre)) << 32) | (unsigned)lat;
            } else {
                key = 0xFFFFFFFF00000000ull | (unsigned)lat;
            }
            skey2[slot] = key;
        }
    }
    __syncthreads();
    for (int ks = 2; ks <= SORT2; ks <<= 1) {
        for (int jj = ks >> 1; jj > 0; jj >>= 1) {
            int i = tid;
            if (i < SORT2) {
                int ixj = i ^ jj;
                if (ixj > i) {
                    bool up = ((i & ks) == 0);
                    unsigned long long a = skey2[i], b2 = skey2[ixj];
                    if (up ? (a > b2) : (a < b2)) { skey2[i] = b2; skey2[ixj] = a; }
                }
            }
            __syncthreads();
        }
    }
    int b = p >> 8, hw = p & 255;
    if (tid < 32) {
        unsigned long long key = skey2[tid];
        unsigned int fb = 0xFFFFFFFFu - (unsigned int)(key >> 32);
        float act = fmaxf(__uint_as_float(fb), 0.0f);
        int lat = (int)(key & 16383u);
        sa[tid] = act;
        si[tid] = lat;
        out_acts[(size_t)b * 8192 + tid * 256 + hw] = act;
        out_idx[(size_t)b * 8192 + tid * 256 + hw] = (float)lat;
    }
    __syncthreads();
    float a0 = dec_b[tid], a1 = dec_b[tid + 256];
    for (int j = 0; j < 32; j++) {
        float a = sa[j];
        const unsigned short* r = dwT + (size_t)si[j] * 512;
        a0 += a * bf2f(r[tid]);
        a1 += a * bf2f(r[tid + 256]);
    }
    size_t o0 = (size_t)b * 131072 + (size_t)tid * 256 + hw;
    size_t o1 = o0 + 65536;
    out_sae[o0] = a0;
    out_sae[o1] = a1;
    float e0 = a0 - xrow[tid], e1 = a1 - xrow[tid + 256];
    red[tid] = (double)e0 * e0 + (double)e1 * e1;
    __syncthreads();
    for (int s = 128; s; s >>= 1) {
        if (tid < s) red[tid] += red[tid + s];
        __syncthreads();
    }
    if (tid == 0) atomicAdd(l2acc, red[0]);
}

// ---------------- finalize fvu ----------------
__global__ __launch_bounds__(256) void k_fin(const double* __restrict__ l2, const double* __restrict__ S,
                                             const double* __restrict__ Q, float* __restrict__ out_sc) {
    __shared__ double red[256];
    int tid = threadIdx.x;
    double tv = 0;
    for (int c = tid; c < 512; c += 256) tv += Q[c] - S[c] * S[c] * (1.0 / 4096.0);
    red[tid] = tv;
    __syncthreads();
    for (int s = 128; s; s >>= 1) {
        if (tid < s) red[tid] += red[tid + s];
        __syncthreads();
    }
    if (tid == 0) {
        double fvu = l2[0] / red[0];
        out_sc[0] = (float)fvu;
        out_sc[1] = 0.0f;
        out_sc[2] = 0.0f;
    }
}

extern "C" void kernel_launch(void* const* d_in, const int* in_sizes, int n_in,
                              void* d_out, int out_size, void* d_ws, size_t ws_size,
                              hipStream_t stream) {
    const float* x = (const float*)d_in[0];
    const float* enc_w = (const float*)d_in[1];
    const float* enc_b = (const float*)d_in[2];
    const float* dec_w = (const float*)d_in[3];
    const float* dec_b = (const float*)d_in[4];
    (void)in_sizes; (void)n_in; (void)out_size; (void)ws_size;

    char* ws = (char*)d_ws;
    float* xTf = (float*)ws;                                   //  8 MB
    signed char* xq = (signed char*)(ws + 8388608);            //  2 MB
    signed char* wq = (signed char*)(ws + 10485760);           //  8 MB
    unsigned short* dwT = (unsigned short*)(ws + 18874368);    // 16 MB
    unsigned int* cand = (unsigned int*)(ws + 35651584);       //  3.67 MB (4096*224*4)
    // contiguous zero-init region: cnt | thrS | S | Q | l2
    int* cnt = (int*)(ws + 39321600);                          // 16 KB
    float* thrS = (float*)(ws + 39337984);                     // 16 KB
    double* S = (double*)(ws + 39354368);                      //  4 KB
    double* Q = (double*)(ws + 39358464);                      //  4 KB
    double* l2 = (double*)(ws + 39362560);                     //  8 B
    float* sx = (float*)(ws + 39366656);                       // 16 KB
    float* sw = (float*)(ws + 39383040);                       // 64 KB

    float* out = (float*)d_out;   // reference outputs are float32
    float* out_sae = out;
    float* out_acts = out + 2097152;
    float* out_idx = out + 2228224;
    float* out_sc = out + 2359296;

    hipMemsetAsync(cnt, 0, 16384 + 16384 + 4096 + 4096 + 8, stream);

    t1_x<<<dim3(8, 4, 16), 256, 0, stream>>>(x, xTf, thrS, S, Q);
    k_qx<<<1024, 256, 0, stream>>>(xTf, xq, sx);
    k_qw<<<4096, 256, 0, stream>>>(enc_w, wq, sw);
    t3_decw<<<dim3(256, 8), 256, 0, stream>>>(dec_w, dwT);
    k_gemm<<<dim3(128, 32), 256, 0, stream>>>(xq, wq, sx, sw, thrS, cnt, cand);
    k_topk<<<4096, 256, 0, stream>>>(xTf, enc_w, enc_b, cnt, cand, dwT, dec_b,
                                     out_acts, out_idx, out_sae, l2);
    k_fin<<<1, 256, 0, stream>>>(l2, S, Q, out_sc);
}

// Round 17
// 285.451 us; speedup vs baseline: 1.2449x; 1.0353x over previous
//
#include <hip/hip_runtime.h>
#include <stdint.h>

typedef __attribute__((ext_vector_type(4))) int i32x4;

#define TN 2.45f          // normalized filter threshold (units of s_p)
#define PMARG 0.10f       // exact-rescore pool margin below approx rank-32
#define CAP 224
#define SORT2 128

__device__ inline float bf2f(unsigned short u) { return __uint_as_float(((unsigned int)u) << 16); }
__device__ inline unsigned short f2bf(float f) {
    unsigned int x = __float_as_uint(f);
    return (unsigned short)((x + 0x7FFFu + ((x >> 16) & 1u)) >> 16);  // RNE
}

template <typename T>
__device__ inline void gload16(const T* g, T* l) {
    __builtin_amdgcn_global_load_lds((const __attribute__((address_space(1))) void*)g,
                                     (__attribute__((address_space(3))) void*)l, 16, 0, 0);
}

// ---- T1: x [16][512][256] -> xT [4096][512] f32 + ||x_p||^2 + per-channel S/Q ----
__global__ __launch_bounds__(256) void t1_x(const float* __restrict__ x, float* __restrict__ xTf,
                                            float* __restrict__ thrS,
                                            double* __restrict__ S, double* __restrict__ Q) {
    __shared__ float tile[64][65];
    int b = blockIdx.z, c0 = blockIdx.x * 64, hw0 = blockIdx.y * 64;
    int tid = threadIdx.x, g = tid >> 6, ln = tid & 63;
    for (int i = 0; i < 16; i++) {
        int cl = g * 16 + i;
        tile[cl][ln] = x[(size_t)(b * 512 + c0 + cl) * 256 + hw0 + ln];
    }
    __syncthreads();
    float s1 = 0.0f, s2 = 0.0f;
    for (int i = 0; i < 16; i++) {
        int hl = g * 16 + i;
        float v = tile[ln][hl];
        xTf[(size_t)(b * 256 + hw0 + hl) * 512 + c0 + ln] = v;
        s1 += v;
        s2 += v * v;
        float s = v * v;
        for (int off = 32; off; off >>= 1) s += __shfl_down(s, off, 64);
        if (ln == 0) atomicAdd(&thrS[b * 256 + hw0 + hl], s);
    }
    atomicAdd(&S[c0 + ln], (double)s1);
    atomicAdd(&Q[c0 + ln], (double)s2);
}

// ---- quantize [N][512] f32 rows to int8, per-row max scale (x and enc_w in one launch) ----
__device__ inline void quant_row(const float* __restrict__ src, signed char* __restrict__ dst,
                                 float* __restrict__ scale, int row, int lane) {
    const float4* s4 = (const float4*)(src + (size_t)row * 512);
    float4 a = s4[lane * 2], b = s4[lane * 2 + 1];
    float m = fmaxf(fmaxf(fmaxf(fabsf(a.x), fabsf(a.y)), fmaxf(fabsf(a.z), fabsf(a.w))),
                    fmaxf(fmaxf(fabsf(b.x), fabsf(b.y)), fmaxf(fabsf(b.z), fabsf(b.w))));
    for (int off = 32; off; off >>= 1) m = fmaxf(m, __shfl_xor(m, off, 64));
    m = fmaxf(m, 1e-20f);
    float inv = 127.0f / m;
    int q0 = __float2int_rn(a.x * inv), q1 = __float2int_rn(a.y * inv);
    int q2 = __float2int_rn(a.z * inv), q3 = __float2int_rn(a.w * inv);
    int q4 = __float2int_rn(b.x * inv), q5 = __float2int_rn(b.y * inv);
    int q6 = __float2int_rn(b.z * inv), q7 = __float2int_rn(b.w * inv);
    unsigned int w0 = (q0 & 255) | ((q1 & 255) << 8) | ((q2 & 255) << 16) | ((unsigned)(q3 & 255) << 24);
    unsigned int w1 = (q4 & 255) | ((q5 & 255) << 8) | ((q6 & 255) << 16) | ((unsigned)(q7 & 255) << 24);
    *(uint2*)(dst + (size_t)row * 512 + lane * 8) = make_uint2(w0, w1);
    if (lane == 0) scale[row] = m * (1.0f / 127.0f);
}

__global__ __launch_bounds__(256) void k_quant(const float* __restrict__ xTf, signed char* __restrict__ xq,
                                               float* __restrict__ sx, const float* __restrict__ enc_w,
                                               signed char* __restrict__ wq, float* __restrict__ sw) {
    int r = blockIdx.x * 4 + (threadIdx.x >> 6), lane = threadIdx.x & 63;
    if (r < 4096) quant_row(xTf, xq, sx, r, lane);
    else quant_row(enc_w, wq, sw, r - 4096, lane);
}

// ---------------- T3: dec_w [512][16384] -> dec_wT [16384][512] bf16 ----------------
__global__ __launch_bounds__(256) void t3_decw(const float* __restrict__ w, unsigned short* __restrict__ wT) {
    __shared__ float tile[64][65];
    int l0 = blockIdx.x * 64, d0 = blockIdx.y * 64;
    int tid = threadIdx.x, g = tid >> 6, ln = tid & 63;
    for (int i = 0; i < 16; i++) {
        int dl = g * 16 + i;
        tile[dl][ln] = w[(size_t)(d0 + dl) * 16384 + l0 + ln];
    }
    __syncthreads();
    for (int i = 0; i < 16; i++) {
        int ll = g * 16 + i;
        wT[(size_t)(l0 + ll) * 512 + d0 + ln] = f2bf(tile[ln][ll]);
    }
}

// ---- GEMM int8: 128x128, BK=64, 256 thr, 3-buf 48KB (3 blocks/CU) + depth-2 counted vmcnt(4) ----
// Combines R16's TLP with R8/R12's counted-vmcnt pipeline. LDS row = 64B = 4 slots;
// read slot ^= (r>>1)&3 (2-way free); staging source pre-swizzled (involution).
#define SBAR                                   \
    __builtin_amdgcn_sched_barrier(0);         \
    __builtin_amdgcn_s_barrier();              \
    __builtin_amdgcn_sched_barrier(0);
#define VMW4 { asm volatile("s_waitcnt vmcnt(4)" ::: "memory"); __builtin_amdgcn_sched_barrier(0); }
#define VMW0 { asm volatile("s_waitcnt vmcnt(0)" ::: "memory"); __builtin_amdgcn_sched_barrier(0); }

__global__ __launch_bounds__(256) void k_gemm(const signed char* __restrict__ xq,
                                              const signed char* __restrict__ wq,
                                              const float* __restrict__ sx, const float* __restrict__ sw,
                                              const float* __restrict__ thrS,
                                              int* __restrict__ cnt, unsigned int* __restrict__ cand) {
    __shared__ __align__(16) signed char As[3][128 * 64];  // 3 x 8KB
    __shared__ __align__(16) signed char Bs[3][128 * 64];  // 3 x 8KB  (tot 48KB -> 3 blocks/CU)
    int tid = threadIdx.x, wid = tid >> 6, lane = tid & 63;

    // XCD swizzle (bijective, 4096 blocks = 8 x 512): XCD owns 16 n-blocks (1MB B slice)
    int lin = blockIdx.x + blockIdx.y * gridDim.x;   // grid (128 n, 32 m)
    int swz = (lin & 7) * 512 + (lin >> 3);
    int bx = swz >> 5;          // n-block 0..127
    int by = swz & 31;          // m-block 0..31
    int m0 = by * 128, n0 = bx * 128;
    int wr = wid >> 1, wc = wid & 1;   // 2x2 waves; per-wave 64x64

    i32x4 acc[4][4];
#pragma unroll
    for (int mi = 0; mi < 4; mi++)
#pragma unroll
        for (int ni = 0; ni < 4; ni++)
#pragma unroll
            for (int j = 0; j < 4; j++) acc[mi][ni][j] = 0;

    int srow = lane >> 2;                 // 0..15 within chunk

#define STAGE(bufi, kt)                                                                            \
    {                                                                                              \
        signed char* Ad = &As[bufi][0];                                                            \
        signed char* Bd = &Bs[bufi][0];                                                            \
        _Pragma("unroll")                                                                          \
        for (int i_ = 0; i_ < 2; i_++) {                                                           \
            int ch_ = wid * 2 + i_;                                                                \
            int row_ = ch_ * 16 + srow;                                                            \
            int sc_ = (((lane & 3) ^ ((row_ >> 1) & 3)) << 4);                                     \
            gload16(xq + (size_t)(m0 + row_) * 512 + (kt) + sc_, Ad + ch_ * 1024);                 \
            gload16(wq + (size_t)(n0 + row_) * 512 + (kt) + sc_, Bd + ch_ * 1024);                 \
        }                                                                                          \
    }

    STAGE(0, 0)
    STAGE(1, 64)     // depth-2: 8 loads/wave in flight
#pragma unroll
    for (int t = 0; t < 8; t++) {
        int cur = t % 3;
        if (t < 7) VMW4      // tile t's 4 loads done; tile t+1's 4 stay in flight
        else VMW0
        SBAR                  // tile t visible; readers of buf (t+2)%3 retired (own lgkm + barrier)
        if (t < 6) STAGE((t + 2) % 3, (t + 2) * 64)
        const signed char* Ac = &As[cur][0];
        const signed char* Bc = &Bs[cur][0];
        i32x4 a[4], b[4];
#pragma unroll
        for (int mi = 0; mi < 4; mi++) {
            int r = wr * 64 + mi * 16 + (lane & 15);
            int slot = (lane >> 4) ^ ((r >> 1) & 3);
            a[mi] = *(const i32x4*)&Ac[r * 64 + slot * 16];
        }
#pragma unroll
        for (int ni = 0; ni < 4; ni++) {
            int r = wc * 64 + ni * 16 + (lane & 15);
            int slot = (lane >> 4) ^ ((r >> 1) & 3);
            b[ni] = *(const i32x4*)&Bc[r * 64 + slot * 16];
        }
#pragma unroll
        for (int mi = 0; mi < 4; mi++)
#pragma unroll
            for (int ni = 0; ni < 4; ni++)
                acc[mi][ni] = __builtin_amdgcn_mfma_i32_16x16x64_i8(a[mi], b[ni], acc[mi][ni], 0, 0, 0);
    }
#undef STAGE

    // filter epilogue: v = dot * sx[pixel] * sw[lat];  C/D row=(lane>>4)*4+j, col=lane&15
    float swl[4];
#pragma unroll
    for (int ni = 0; ni < 4; ni++) swl[ni] = sw[n0 + wc * 64 + ni * 16 + (lane & 15)];
#pragma unroll
    for (int mi = 0; mi < 4; mi++)
#pragma unroll
        for (int j = 0; j < 4; j++) {
            int pixel = m0 + wr * 64 + mi * 16 + (lane >> 4) * 4 + j;
            float tv = TN * sqrtf(thrS[pixel] * (1.0f / 512.0f));
            float sxp = sx[pixel];
#pragma unroll
            for (int ni = 0; ni < 4; ni++) {
                float v = (float)acc[mi][ni][j] * (sxp * swl[ni]);
                if (v >= tv) {
                    int lat = n0 + wc * 64 + ni * 16 + (lane & 15);
                    int slot = atomicAdd(&cnt[pixel], 1);
                    if (slot < CAP) cand[pixel * CAP + slot] = ((unsigned)f2bf(v) << 16) | (unsigned)lat;
                }
            }
        }
}

// ---- top-32 + decode fused: binary-search approx rank-32, exact seqFMA rescore pool, sort ----
__global__ __launch_bounds__(256) void k_topk(const float* __restrict__ xTf, const float* __restrict__ enc_w,
                                              const float* __restrict__ enc_b, const int* __restrict__ cnt,
                                              const unsigned int* __restrict__ cand,
                                              const unsigned short* __restrict__ dwT,
                                              const float* __restrict__ dec_b,
                                              float* __restrict__ out_acts, float* __restrict__ out_idx,
                                              float* __restrict__ out_sae, double* __restrict__ l2acc) {
    __shared__ __align__(16) float xrow[512];
    __shared__ unsigned long long skey2[SORT2];
    __shared__ int npool;
    __shared__ float sa[32];
    __shared__ int si[32];
    __shared__ double red[256];
    int p = blockIdx.x, tid = threadIdx.x;
    for (int i = tid; i < 512; i += 256) xrow[i] = xTf[(size_t)p * 512 + i];
    if (tid < SORT2) skey2[tid] = ~0ull;
    if (tid == 0) npool = 0;
    int c = cnt[p];
    if (c > CAP) c = CAP;
    unsigned int pk = (tid < c) ? cand[p * CAP + tid] : 0u;
    unsigned int bfb = pk >> 16;
    int lo = 0, hi = 65535;
    for (int it = 0; it < 16; it++) {
        int mid = (lo + hi + 1) >> 1;
        int n = __syncthreads_count(tid < c && bfb >= (unsigned)mid);
        if (n >= 32) lo = mid; else hi = mid - 1;
    }
    float pthr = bf2f((unsigned short)lo) - PMARG;
    __syncthreads();
    if (tid < c && bf2f((unsigned short)bfb) >= pthr) {
        int slot = atomicAdd(&npool, 1);
        if (slot < SORT2) {
            int lat = (int)(pk & 16383u);
            const float4* w4 = (const float4*)(enc_w + (size_t)lat * 512);
            const float4* x4 = (const float4*)xrow;
            float acc = 0.0f;
            for (int q = 0; q < 128; q++) {
                float4 w = w4[q];
                float4 xv = x4[q];
                acc = __fmaf_rn(xv.x, w.x, acc);
                acc = __fmaf_rn(xv.y, w.y, acc);
                acc = __fmaf_rn(xv.z, w.z, acc);
                acc = __fmaf_rn(xv.w, w.w, acc);
            }
            float pre = __fadd_rn(acc, enc_b[lat]);
            unsigned long long key;
            if (pre > 0.0f) {
                key = ((unsigned long long)(0xFFFFFFFFu - __float_as_uint(pre)) << 32) | (unsigned)lat;
            } else {
                key = 0xFFFFFFFF00000000ull | (unsigned)lat;
            }
            skey2[slot] = key;
        }
    }
    __syncthreads();
    for (int ks = 2; ks <= SORT2; ks <<= 1) {
        for (int jj = ks >> 1; jj > 0; jj >>= 1) {
            int i = tid;
            if (i < SORT2) {
                int ixj = i ^ jj;
                if (ixj > i) {
                    bool up = ((i & ks) == 0);
                    unsigned long long a = skey2[i], b2 = skey2[ixj];
                    if (up ? (a > b2) : (a < b2)) { skey2[i] = b2; skey2[ixj] = a; }
                }
            }
            __syncthreads();
        }
    }
    int b = p >> 8, hw = p & 255;
    if (tid < 32) {
        unsigned long long key = skey2[tid];
        unsigned int fb = 0xFFFFFFFFu - (unsigned int)(key >> 32);
        float act = fmaxf(__uint_as_float(fb), 0.0f);
        int lat = (int)(key & 16383u);
        sa[tid] = act;
        si[tid] = lat;
        out_acts[(size_t)b * 8192 + tid * 256 + hw] = act;
        out_idx[(size_t)b * 8192 + tid * 256 + hw] = (float)lat;
    }
    __syncthreads();
    float a0 = dec_b[tid], a1 = dec_b[tid + 256];
    for (int j = 0; j < 32; j++) {
        float a = sa[j];
        const unsigned short* r = dwT + (size_t)si[j] * 512;
        a0 += a * bf2f(r[tid]);
        a1 += a * bf2f(r[tid + 256]);
    }
    size_t o0 = (size_t)b * 131072 + (size_t)tid * 256 + hw;
    size_t o1 = o0 + 65536;
    out_sae[o0] = a0;
    out_sae[o1] = a1;
    float e0 = a0 - xrow[tid], e1 = a1 - xrow[tid + 256];
    red[tid] = (double)e0 * e0 + (double)e1 * e1;
    __syncthreads();
    for (int s = 128; s; s >>= 1) {
        if (tid < s) red[tid] += red[tid + s];
        __syncthreads();
    }
    if (tid == 0) atomicAdd(l2acc, red[0]);
}

// ---------------- finalize fvu ----------------
__global__ __launch_bounds__(256) void k_fin(const double* __restrict__ l2, const double* __restrict__ S,
                                             const double* __restrict__ Q, float* __restrict__ out_sc) {
    __shared__ double red[256];
    int tid = threadIdx.x;
    double tv = 0;
    for (int c = tid; c < 512; c += 256) tv += Q[c] - S[c] * S[c] * (1.0 / 4096.0);
    red[tid] = tv;
    __syncthreads();
    for (int s = 128; s; s >>= 1) {
        if (tid < s) red[tid] += red[tid + s];
        __syncthreads();
    }
    if (tid == 0) {
        double fvu = l2[0] / red[0];
        out_sc[0] = (float)fvu;
        out_sc[1] = 0.0f;
        out_sc[2] = 0.0f;
    }
}

extern "C" void kernel_launch(void* const* d_in, const int* in_sizes, int n_in,
                              void* d_out, int out_size, void* d_ws, size_t ws_size,
                              hipStream_t stream) {
    const float* x = (const float*)d_in[0];
    const float* enc_w = (const float*)d_in[1];
    const float* enc_b = (const float*)d_in[2];
    const float* dec_w = (const float*)d_in[3];
    const float* dec_b = (const float*)d_in[4];
    (void)in_sizes; (void)n_in; (void)out_size; (void)ws_size;

    char* ws = (char*)d_ws;
    float* xTf = (float*)ws;                                   //  8 MB
    signed char* xq = (signed char*)(ws + 8388608);            //  2 MB
    signed char* wq = (signed char*)(ws + 10485760);           //  8 MB
    unsigned short* dwT = (unsigned short*)(ws + 18874368);    // 16 MB
    unsigned int* cand = (unsigned int*)(ws + 35651584);       //  3.67 MB (4096*224*4)
    // contiguous zero-init region: cnt | thrS | S | Q | l2
    int* cnt = (int*)(ws + 39321600);                          // 16 KB
    float* thrS = (float*)(ws + 39337984);                     // 16 KB
    double* S = (double*)(ws + 39354368);                      //  4 KB
    double* Q = (double*)(ws + 39358464);                      //  4 KB
    double* l2 = (double*)(ws + 39362560);                     //  8 B
    float* sx = (float*)(ws + 39366656);                       // 16 KB
    float* sw = (float*)(ws + 39383040);                       // 64 KB

    float* out = (float*)d_out;   // reference outputs are float32
    float* out_sae = out;
    float* out_acts = out + 2097152;
    float* out_idx = out + 2228224;
    float* out_sc = out + 2359296;

    hipMemsetAsync(cnt, 0, 16384 + 16384 + 4096 + 4096 + 8, stream);

    t1_x<<<dim3(8, 4, 16), 256, 0, stream>>>(x, xTf, thrS, S, Q);
    k_quant<<<5120, 256, 0, stream>>>(xTf, xq, sx, enc_w, wq, sw);
    t3_decw<<<dim3(256, 8), 256, 0, stream>>>(dec_w, dwT);
    k_gemm<<<dim3(128, 32), 256, 0, stream>>>(xq, wq, sx, sw, thrS, cnt, cand);
    k_topk<<<4096, 256, 0, stream>>>(xTf, enc_w, enc_b, cnt, cand, dwT, dec_b,
                                     out_acts, out_idx, out_sae, l2);
    k_fin<<<1, 256, 0, stream>>>(l2, S, Q, out_sc);
}